// Round 2
// baseline (2175.580 us; speedup 1.0000x reference)
//
#include <hip/hip_runtime.h>

#define D 128
#define DV 32   // D/4 float4s per row
#define GR 64   // rows per GEMM block

static inline int ceil_div_ll(long long a, int b) { return (int)((a + b - 1) / b); }

// deg[i] = 1.0 (self loop)
__global__ void k_deg_init(float* __restrict__ deg, int n) {
    int i = blockIdx.x * blockDim.x + threadIdx.x;
    if (i < n) deg[i] = 1.0f;
}

// deg[col[e]] += 1
__global__ void k_deg_count(const int* __restrict__ ei, float* __restrict__ deg, int E) {
    int e = blockIdx.x * blockDim.x + threadIdx.x;
    if (e < E) {
        int c = ei[(long long)E + e];
        unsafeAtomicAdd(&deg[c], 1.0f);
    }
}

// deg -> deg^(-1/2)   (deg >= 1 always due to self loops)
__global__ void k_deg_finalize(float* __restrict__ deg, int n) {
    int i = blockIdx.x * blockDim.x + threadIdx.x;
    if (i < n) deg[i] = 1.0f / sqrtf(deg[i]);
}

// ew[e] = dinv[row] * dinv[col]
__global__ void k_edge_w(const int* __restrict__ ei, const float* __restrict__ dinv,
                         float* __restrict__ ew, int E) {
    int e = blockIdx.x * blockDim.x + threadIdx.x;
    if (e < E) {
        int r = ei[e];
        int c = ei[(long long)E + e];
        ew[e] = dinv[r] * dinv[c];
    }
}

// xout[i][:] = dinv[i]^2 * xin[i][:]   (self-loop term; fully overwrites xout)
__global__ void k_self(const float4* __restrict__ xin, const float* __restrict__ dinv,
                       float4* __restrict__ xout, int n) {
    long long idx = (long long)blockIdx.x * blockDim.x + threadIdx.x;
    if (idx < (long long)n * DV) {
        int i = (int)(idx >> 5);
        float s = dinv[i];
        s *= s;
        float4 v = xin[idx];
        v.x *= s; v.y *= s; v.z *= s; v.w *= s;
        xout[idx] = v;
    }
}

// xout[row[e]][:] += ew[e] * xin[col[e]][:]   (32 threads per edge, float4 each)
__global__ void k_scatter(const float4* __restrict__ xin, const int* __restrict__ ei,
                          const float* __restrict__ ew, float* __restrict__ xout, int E) {
    long long idx = (long long)blockIdx.x * blockDim.x + threadIdx.x;
    long long total = (long long)E * DV;
    if (idx >= total) return;
    int e = (int)(idx >> 5);
    int q = (int)(idx & 31);
    int r = ei[e];
    int c = ei[(long long)E + e];
    float w = ew[e];
    float4 v = xin[(long long)c * DV + q];
    float* dst = xout + (long long)r * D + q * 4;
    unsafeAtomicAdd(dst + 0, w * v.x);
    unsafeAtomicAdd(dst + 1, w * v.y);
    unsafeAtomicAdd(dst + 2, w * v.z);
    unsafeAtomicAdd(dst + 3, w * v.w);
}

// xout[r][:] = xin[r][:] @ W^T + b for rows [blockIdx*GR, +GR). NOT in place.
__global__ __launch_bounds__(256) void k_gemm(const float* __restrict__ xin,
                                              const float* __restrict__ Wm,
                                              const float* __restrict__ bias,
                                              float* __restrict__ xout, int n) {
    __shared__ float shx[D * GR];   // [k][r], 32 KB
    __shared__ float shw[D * D];    // [k][j], 64 KB
    __shared__ float shb[D];

    const int tid = threadIdx.x;
    const long long base = (long long)blockIdx.x * GR;

    // Load W transposed: shw[k][j] = W[j][k]
    {
        int j = tid & 127;
        int k0 = (tid >> 7) << 2;   // 0 or 4
        for (int kk = k0; kk < D; kk += 8) {
            const float4 v = *(const float4*)(Wm + (long long)j * D + kk);
            shw[(kk + 0) * D + j] = v.x;
            shw[(kk + 1) * D + j] = v.y;
            shw[(kk + 2) * D + j] = v.z;
            shw[(kk + 3) * D + j] = v.w;
        }
    }
    // Load x tile transposed: shx[k][r] = xin[base+r][k]
    {
        int r = tid & 63;
        int k0 = (tid >> 6) << 2;   // 0,4,8,12
        long long row = base + r;
        if (row < n) {
            for (int kk = k0; kk < D; kk += 16) {
                const float4 v = *(const float4*)(xin + row * D + kk);
                shx[(kk + 0) * GR + r] = v.x;
                shx[(kk + 1) * GR + r] = v.y;
                shx[(kk + 2) * GR + r] = v.z;
                shx[(kk + 3) * GR + r] = v.w;
            }
        } else {
            for (int kk = k0; kk < D; kk += 16) {
                shx[(kk + 0) * GR + r] = 0.0f;
                shx[(kk + 1) * GR + r] = 0.0f;
                shx[(kk + 2) * GR + r] = 0.0f;
                shx[(kk + 3) * GR + r] = 0.0f;
            }
        }
    }
    if (tid < D) shb[tid] = bias[tid];
    __syncthreads();

    const int ty = tid >> 4;   // 0..15 -> 4 rows each
    const int tx = tid & 15;   // 0..15 -> 8 cols each

    float acc[4][8];
#pragma unroll
    for (int i = 0; i < 4; ++i)
#pragma unroll
        for (int j = 0; j < 8; ++j) acc[i][j] = 0.0f;

    const float* px = shx + ty * 4;
    const float* pw = shw + tx * 8;
    for (int k = 0; k < D; ++k) {
        const float4 xa = *(const float4*)(px + k * GR);
        const float4 wa = *(const float4*)(pw + k * D);
        const float4 wb = *(const float4*)(pw + k * D + 4);
        const float xr[4] = {xa.x, xa.y, xa.z, xa.w};
        const float wc[8] = {wa.x, wa.y, wa.z, wa.w, wb.x, wb.y, wb.z, wb.w};
#pragma unroll
        for (int i = 0; i < 4; ++i)
#pragma unroll
            for (int j = 0; j < 8; ++j) acc[i][j] += xr[i] * wc[j];
    }

#pragma unroll
    for (int i = 0; i < 4; ++i) {
        long long row = base + ty * 4 + i;
        if (row < n) {
            float4 o0, o1;
            o0.x = acc[i][0] + shb[tx * 8 + 0];
            o0.y = acc[i][1] + shb[tx * 8 + 1];
            o0.z = acc[i][2] + shb[tx * 8 + 2];
            o0.w = acc[i][3] + shb[tx * 8 + 3];
            o1.x = acc[i][4] + shb[tx * 8 + 4];
            o1.y = acc[i][5] + shb[tx * 8 + 5];
            o1.z = acc[i][6] + shb[tx * 8 + 6];
            o1.w = acc[i][7] + shb[tx * 8 + 7];
            *(float4*)(xout + row * D + tx * 8) = o0;
            *(float4*)(xout + row * D + tx * 8 + 4) = o1;
        }
    }
}

extern "C" void kernel_launch(void* const* d_in, const int* in_sizes, int n_in,
                              void* d_out, int out_size, void* d_ws, size_t ws_size,
                              hipStream_t stream) {
    const float* x = (const float*)d_in[0];
    const int* ei = (const int*)d_in[1];     // harness delivers integer inputs as int32
    const float* Wm = (const float*)d_in[2];
    const float* bias = (const float*)d_in[3];
    float* out = (float*)d_out;

    const int n = in_sizes[0] / D;
    const int E = in_sizes[1] / 2;

    // Workspace layout (floats): deg/dinv [n] | ew [E] | x1 [n*D]  (~54 MB)
    float* ws = (float*)d_ws;
    float* deg = ws;
    float* ew = ws + (((long long)n + 127) & ~127LL);
    float* x1 = ew + (((long long)E + 127) & ~127LL);

    const int B = 256;

    k_deg_init<<<ceil_div_ll(n, B), B, 0, stream>>>(deg, n);
    k_deg_count<<<ceil_div_ll(E, B), B, 0, stream>>>(ei, deg, E);
    k_deg_finalize<<<ceil_div_ll(n, B), B, 0, stream>>>(deg, n);
    k_edge_w<<<ceil_div_ll(E, B), B, 0, stream>>>(ei, deg, ew, E);

    // hop 1: out = A_norm @ x      (out fully overwritten by k_self first)
    k_self<<<ceil_div_ll((long long)n * DV, B), B, 0, stream>>>(
        (const float4*)x, deg, (float4*)out, n);
    k_scatter<<<ceil_div_ll((long long)E * DV, B), B, 0, stream>>>(
        (const float4*)x, ei, ew, out, E);

    // hop 2: x1 = A_norm @ out
    k_self<<<ceil_div_ll((long long)n * DV, B), B, 0, stream>>>(
        (const float4*)out, deg, (float4*)x1, n);
    k_scatter<<<ceil_div_ll((long long)E * DV, B), B, 0, stream>>>(
        (const float4*)out, ei, ew, x1, E);

    // out = x1 @ W^T + b   (not in place)
    k_gemm<<<ceil_div_ll(n, GR), B, 0, stream>>>(x1, Wm, bias, out, n);
}

// Round 3
// 316.993 us; speedup vs baseline: 6.8632x; 6.8632x over previous
//
#include <hip/hip_runtime.h>

#define D 128
#define GR 64   // rows per GEMM block
#define SCAN_B 1024

static inline int ceil_div_ll(long long a, int b) { return (int)((a + b - 1) / b); }

// deg[i] = 1.0 (self loop), cnt[i] = 0
__global__ void k_init(float* __restrict__ deg, int* __restrict__ cnt, int n) {
    int i = blockIdx.x * blockDim.x + threadIdx.x;
    if (i < n) { deg[i] = 1.0f; cnt[i] = 0; }
}

// deg[col[e]] += 1 (normalization);  cnt[row[e]] += 1 (CSR histogram)
__global__ void k_count(const int* __restrict__ ei, float* __restrict__ deg,
                        int* __restrict__ cnt, int E) {
    int e = blockIdx.x * blockDim.x + threadIdx.x;
    if (e < E) {
        int r = ei[e];
        int c = ei[(long long)E + e];
        unsafeAtomicAdd(&deg[c], 1.0f);
        atomicAdd(&cnt[r], 1);
    }
}

// deg -> deg^(-1/2)
__global__ void k_deg_finalize(float* __restrict__ deg, int n) {
    int i = blockIdx.x * blockDim.x + threadIdx.x;
    if (i < n) deg[i] = 1.0f / sqrtf(deg[i]);
}

// ---- two-level exclusive scan of cnt -> rp ----
__global__ __launch_bounds__(SCAN_B) void k_scan1(const int* __restrict__ cnt,
                                                  int* __restrict__ rp,
                                                  int* __restrict__ bsum, int n) {
    __shared__ int sh[SCAN_B];
    const int tid = threadIdx.x;
    const int i = blockIdx.x * SCAN_B + tid;
    int v = (i < n) ? cnt[i] : 0;
    sh[tid] = v;
    __syncthreads();
    for (int off = 1; off < SCAN_B; off <<= 1) {
        int t = (tid >= off) ? sh[tid - off] : 0;
        __syncthreads();
        sh[tid] += t;
        __syncthreads();
    }
    if (i < n) rp[i] = sh[tid] - v;          // local exclusive
    if (tid == SCAN_B - 1) bsum[blockIdx.x] = sh[SCAN_B - 1];
}

__global__ __launch_bounds__(SCAN_B) void k_scan2(int* __restrict__ bsum,
                                                  int* __restrict__ rp, int nb, int n) {
    __shared__ int sh[SCAN_B];
    const int tid = threadIdx.x;
    int v = (tid < nb) ? bsum[tid] : 0;
    sh[tid] = v;
    __syncthreads();
    for (int off = 1; off < SCAN_B; off <<= 1) {
        int t = (tid >= off) ? sh[tid - off] : 0;
        __syncthreads();
        sh[tid] += t;
        __syncthreads();
    }
    if (tid < nb) bsum[tid] = sh[tid] - v;   // exclusive block offsets
    if (tid == SCAN_B - 1) rp[n] = sh[SCAN_B - 1];  // total (== E)
}

__global__ void k_scan3(int* __restrict__ rp, int* __restrict__ cur,
                        const int* __restrict__ bsum, int n) {
    int i = blockIdx.x * blockDim.x + threadIdx.x;
    if (i < n) {
        int v = rp[i] + bsum[i >> 10];
        rp[i] = v;
        cur[i] = v;
    }
}

// scatter edges into CSR slots; fold edge-weight computation in here
__global__ void k_fill(const int* __restrict__ ei, const float* __restrict__ dinv,
                       int* __restrict__ cur, int* __restrict__ ci,
                       float* __restrict__ cw, int E) {
    int e = blockIdx.x * blockDim.x + threadIdx.x;
    if (e < E) {
        int r = ei[e];
        int c = ei[(long long)E + e];
        float w = dinv[r] * dinv[c];
        int pos = atomicAdd(&cur[r], 1);
        ci[pos] = c;
        cw[pos] = w;
    }
}

// out[r][:] = dinv[r]^2 * x[r][:] + sum_e cw[e] * x[ci[e]][:]
// one wave per row, lane holds float2 (64*2 = 128)
__global__ __launch_bounds__(256) void k_spmm(const float2* __restrict__ xv,
                                              const int* __restrict__ rp,
                                              const int* __restrict__ ci,
                                              const float* __restrict__ cw,
                                              const float* __restrict__ dinv,
                                              float2* __restrict__ outv, int n) {
    const int row = blockIdx.x * 4 + (threadIdx.x >> 6);
    if (row >= n) return;
    const int lane = threadIdx.x & 63;

    float s = dinv[row];
    s *= s;
    float2 acc = xv[row * 64 + lane];
    acc.x *= s; acc.y *= s;

    int e = rp[row];
    const int end = rp[row + 1];
    for (; e + 1 < end; e += 2) {
        int c0 = ci[e];
        int c1 = ci[e + 1];
        float w0 = cw[e];
        float w1 = cw[e + 1];
        float2 v0 = xv[c0 * 64 + lane];
        float2 v1 = xv[c1 * 64 + lane];
        acc.x += w0 * v0.x + w1 * v1.x;
        acc.y += w0 * v0.y + w1 * v1.y;
    }
    if (e < end) {
        int c0 = ci[e];
        float w0 = cw[e];
        float2 v0 = xv[c0 * 64 + lane];
        acc.x += w0 * v0.x;
        acc.y += w0 * v0.y;
    }
    outv[row * 64 + lane] = acc;
}

// xout[r][:] = xin[r][:] @ W^T + b for rows [blockIdx*GR, +GR). NOT in place.
__global__ __launch_bounds__(256) void k_gemm(const float* __restrict__ xin,
                                              const float* __restrict__ Wm,
                                              const float* __restrict__ bias,
                                              float* __restrict__ xout, int n) {
    __shared__ float shx[D * GR];   // [k][r], 32 KB
    __shared__ float shw[D * D];    // [k][j], 64 KB
    __shared__ float shb[D];

    const int tid = threadIdx.x;
    const long long base = (long long)blockIdx.x * GR;

    {
        int j = tid & 127;
        int k0 = (tid >> 7) << 2;
        for (int kk = k0; kk < D; kk += 8) {
            const float4 v = *(const float4*)(Wm + (long long)j * D + kk);
            shw[(kk + 0) * D + j] = v.x;
            shw[(kk + 1) * D + j] = v.y;
            shw[(kk + 2) * D + j] = v.z;
            shw[(kk + 3) * D + j] = v.w;
        }
    }
    {
        int r = tid & 63;
        int k0 = (tid >> 6) << 2;
        long long row = base + r;
        if (row < n) {
            for (int kk = k0; kk < D; kk += 16) {
                const float4 v = *(const float4*)(xin + row * D + kk);
                shx[(kk + 0) * GR + r] = v.x;
                shx[(kk + 1) * GR + r] = v.y;
                shx[(kk + 2) * GR + r] = v.z;
                shx[(kk + 3) * GR + r] = v.w;
            }
        } else {
            for (int kk = k0; kk < D; kk += 16) {
                shx[(kk + 0) * GR + r] = 0.0f;
                shx[(kk + 1) * GR + r] = 0.0f;
                shx[(kk + 2) * GR + r] = 0.0f;
                shx[(kk + 3) * GR + r] = 0.0f;
            }
        }
    }
    if (tid < D) shb[tid] = bias[tid];
    __syncthreads();

    const int ty = tid >> 4;
    const int tx = tid & 15;

    float acc[4][8];
#pragma unroll
    for (int i = 0; i < 4; ++i)
#pragma unroll
        for (int j = 0; j < 8; ++j) acc[i][j] = 0.0f;

    const float* px = shx + ty * 4;
    const float* pw = shw + tx * 8;
    for (int k = 0; k < D; ++k) {
        const float4 xa = *(const float4*)(px + k * GR);
        const float4 wa = *(const float4*)(pw + k * D);
        const float4 wb = *(const float4*)(pw + k * D + 4);
        const float xr[4] = {xa.x, xa.y, xa.z, xa.w};
        const float wc[8] = {wa.x, wa.y, wa.z, wa.w, wb.x, wb.y, wb.z, wb.w};
#pragma unroll
        for (int i = 0; i < 4; ++i)
#pragma unroll
            for (int j = 0; j < 8; ++j) acc[i][j] += xr[i] * wc[j];
    }

#pragma unroll
    for (int i = 0; i < 4; ++i) {
        long long row = base + ty * 4 + i;
        if (row < n) {
            float4 o0, o1;
            o0.x = acc[i][0] + shb[tx * 8 + 0];
            o0.y = acc[i][1] + shb[tx * 8 + 1];
            o0.z = acc[i][2] + shb[tx * 8 + 2];
            o0.w = acc[i][3] + shb[tx * 8 + 3];
            o1.x = acc[i][4] + shb[tx * 8 + 4];
            o1.y = acc[i][5] + shb[tx * 8 + 5];
            o1.z = acc[i][6] + shb[tx * 8 + 6];
            o1.w = acc[i][7] + shb[tx * 8 + 7];
            *(float4*)(xout + row * D + tx * 8) = o0;
            *(float4*)(xout + row * D + tx * 8 + 4) = o1;
        }
    }
}

extern "C" void kernel_launch(void* const* d_in, const int* in_sizes, int n_in,
                              void* d_out, int out_size, void* d_ws, size_t ws_size,
                              hipStream_t stream) {
    const float* x = (const float*)d_in[0];
    const int* ei = (const int*)d_in[1];
    const float* Wm = (const float*)d_in[2];
    const float* bias = (const float*)d_in[3];
    float* out = (float*)d_out;

    const int n = in_sizes[0] / D;
    const int E = in_sizes[1] / 2;
    const int NB = (n + SCAN_B - 1) / SCAN_B;   // scan blocks (<= 1024 assumed)

    // Workspace layout (4-byte units), each region 128-aligned:
    char* ws = (char*)d_ws;
    size_t off = 0;
    auto alloc = [&](long long elems) {
        void* p = ws + off;
        off += (size_t)((elems * 4 + 511) & ~511LL);
        return p;
    };
    float* dinv = (float*)alloc(n);
    int* cnt    = (int*)alloc(n);
    int* rp     = (int*)alloc(n + 1);
    int* cur    = (int*)alloc(n);
    int* bsum   = (int*)alloc(SCAN_B);
    int* ci     = (int*)alloc(E);
    float* cw   = (float*)alloc(E);
    float* x1   = (float*)alloc((long long)n * D);

    const int B = 256;

    k_init<<<ceil_div_ll(n, B), B, 0, stream>>>(dinv, cnt, n);
    k_count<<<ceil_div_ll(E, B), B, 0, stream>>>(ei, dinv, cnt, E);
    k_deg_finalize<<<ceil_div_ll(n, B), B, 0, stream>>>(dinv, n);

    k_scan1<<<NB, SCAN_B, 0, stream>>>(cnt, rp, bsum, n);
    k_scan2<<<1, SCAN_B, 0, stream>>>(bsum, rp, NB, n);
    k_scan3<<<ceil_div_ll(n, B), B, 0, stream>>>(rp, cur, bsum, n);
    k_fill<<<ceil_div_ll(E, B), B, 0, stream>>>(ei, dinv, cur, ci, cw, E);

    // hop 1: out = A_norm @ x
    k_spmm<<<ceil_div_ll(n, 4), B, 0, stream>>>(
        (const float2*)x, rp, ci, cw, dinv, (float2*)out, n);
    // hop 2: x1 = A_norm @ out
    k_spmm<<<ceil_div_ll(n, 4), B, 0, stream>>>(
        (const float2*)out, rp, ci, cw, dinv, (float2*)x1, n);

    // out = x1 @ W^T + b
    k_gemm<<<ceil_div_ll(n, GR), B, 0, stream>>>(x1, Wm, bias, out, n);
}

// Round 4
// 291.728 us; speedup vs baseline: 7.4576x; 1.0866x over previous
//
#include <hip/hip_runtime.h>

#define D 128
#define SCAN_B 1024
#define WPAD 132   // LDS row stride (floats): 16B-aligned, bank-friendly

static inline int ceil_div_ll(long long a, int b) { return (int)((a + b - 1) / b); }

// deg[i] = 1.0 (self loop), cnt[i] = 0
__global__ void k_init(float* __restrict__ deg, int* __restrict__ cnt, int n) {
    int i = blockIdx.x * blockDim.x + threadIdx.x;
    if (i < n) { deg[i] = 1.0f; cnt[i] = 0; }
}

// deg[col[e]] += 1 (normalization);  cnt[row[e]] += 1 (CSR histogram)
__global__ void k_count(const int* __restrict__ ei, float* __restrict__ deg,
                        int* __restrict__ cnt, int E) {
    int e = blockIdx.x * blockDim.x + threadIdx.x;
    if (e < E) {
        int r = ei[e];
        int c = ei[(long long)E + e];
        unsafeAtomicAdd(&deg[c], 1.0f);
        atomicAdd(&cnt[r], 1);
    }
}

// deg -> deg^(-1/2)
__global__ void k_deg_finalize(float* __restrict__ deg, int n) {
    int i = blockIdx.x * blockDim.x + threadIdx.x;
    if (i < n) deg[i] = 1.0f / sqrtf(deg[i]);
}

// ---- two-level exclusive scan of cnt -> rp ----
__global__ __launch_bounds__(SCAN_B) void k_scan1(const int* __restrict__ cnt,
                                                  int* __restrict__ rp,
                                                  int* __restrict__ bsum, int n) {
    __shared__ int sh[SCAN_B];
    const int tid = threadIdx.x;
    const int i = blockIdx.x * SCAN_B + tid;
    int v = (i < n) ? cnt[i] : 0;
    sh[tid] = v;
    __syncthreads();
    for (int off = 1; off < SCAN_B; off <<= 1) {
        int t = (tid >= off) ? sh[tid - off] : 0;
        __syncthreads();
        sh[tid] += t;
        __syncthreads();
    }
    if (i < n) rp[i] = sh[tid] - v;          // local exclusive
    if (tid == SCAN_B - 1) bsum[blockIdx.x] = sh[SCAN_B - 1];
}

__global__ __launch_bounds__(SCAN_B) void k_scan2(int* __restrict__ bsum,
                                                  int* __restrict__ rp, int nb, int n) {
    __shared__ int sh[SCAN_B];
    const int tid = threadIdx.x;
    int v = (tid < nb) ? bsum[tid] : 0;
    sh[tid] = v;
    __syncthreads();
    for (int off = 1; off < SCAN_B; off <<= 1) {
        int t = (tid >= off) ? sh[tid - off] : 0;
        __syncthreads();
        sh[tid] += t;
        __syncthreads();
    }
    if (tid < nb) bsum[tid] = sh[tid] - v;   // exclusive block offsets
    if (tid == SCAN_B - 1) rp[n] = sh[SCAN_B - 1];  // total (== E)
}

__global__ void k_scan3(int* __restrict__ rp, int* __restrict__ cur,
                        const int* __restrict__ bsum, int n) {
    int i = blockIdx.x * blockDim.x + threadIdx.x;
    if (i < n) {
        int v = rp[i] + bsum[i >> 10];
        rp[i] = v;
        cur[i] = v;
    }
}

// scatter edges into CSR slots as packed {col, weight_bits}
__global__ void k_fill(const int* __restrict__ ei, const float* __restrict__ dinv,
                       int* __restrict__ cur, int2* __restrict__ e8, int E) {
    int e = blockIdx.x * blockDim.x + threadIdx.x;
    if (e < E) {
        int r = ei[e];
        int c = ei[(long long)E + e];
        float w = dinv[r] * dinv[c];
        int pos = atomicAdd(&cur[r], 1);
        int2 p; p.x = c; p.y = __float_as_int(w);
        e8[pos] = p;
    }
}

// out[r][:] = dinv[r]^2 * x[r][:] + sum_e w_e * x[col_e][:]
// one wave per row, lane holds float2; 4-edge unrolled batched gathers
__global__ __launch_bounds__(256) void k_spmm(const float2* __restrict__ xv,
                                              const int* __restrict__ rp,
                                              const int2* __restrict__ e8,
                                              const float* __restrict__ dinv,
                                              float2* __restrict__ outv, int n) {
    const int row = blockIdx.x * 4 + (threadIdx.x >> 6);
    if (row >= n) return;
    const int lane = threadIdx.x & 63;

    float s = dinv[row];
    s *= s;
    float2 acc = xv[(long long)row * 64 + lane];
    acc.x *= s; acc.y *= s;

    int e = rp[row];
    const int end = rp[row + 1];
    for (; e + 3 < end; e += 4) {
        const int2 p0 = e8[e], p1 = e8[e + 1], p2 = e8[e + 2], p3 = e8[e + 3];
        const float2 v0 = xv[(long long)p0.x * 64 + lane];
        const float2 v1 = xv[(long long)p1.x * 64 + lane];
        const float2 v2 = xv[(long long)p2.x * 64 + lane];
        const float2 v3 = xv[(long long)p3.x * 64 + lane];
        const float w0 = __int_as_float(p0.y), w1 = __int_as_float(p1.y);
        const float w2 = __int_as_float(p2.y), w3 = __int_as_float(p3.y);
        acc.x += w0 * v0.x + w1 * v1.x + w2 * v2.x + w3 * v3.x;
        acc.y += w0 * v0.y + w1 * v1.y + w2 * v2.y + w3 * v3.y;
    }
    for (; e < end; ++e) {
        const int2 p = e8[e];
        const float2 v = xv[(long long)p.x * 64 + lane];
        const float w = __int_as_float(p.y);
        acc.x += w * v.x;
        acc.y += w * v.y;
    }
    outv[(long long)row * 64 + lane] = acc;
}

// xout[r][colbase + 0..63] = xin[r][:] @ W^T[:, colbase+0..63] + b
// Block: 256 rows x 64 cols, 256 threads, 8 rows x 8 cols per thread.
// Only W staged in LDS ([j][k], stride WPAD=132: 16B-aligned, 2-way banks).
// x rows read from global: 8-lane same-address broadcast, each row fetched
// exactly once per block.
__global__ __launch_bounds__(256, 3) void k_gemm(const float* __restrict__ xin,
                                                 const float* __restrict__ Wm,
                                                 const float* __restrict__ bias,
                                                 float* __restrict__ xout, int n) {
    __shared__ float shw[64 * WPAD];   // ~33.8 KB
    __shared__ float shb[64];

    const int tid = threadIdx.x;
    const int colbase = blockIdx.y * 64;
    const long long rowbase = (long long)blockIdx.x * 256;

    // stage W: 64 cols x 128 k  (W[j][k] row-major, j = output col)
    for (int idx = tid; idx < 64 * 32; idx += 256) {
        const int jl = idx >> 5;
        const int k4 = idx & 31;
        const float4 v = *(const float4*)(Wm + ((long long)(colbase + jl) << 7) + (k4 << 2));
        *(float4*)(shw + jl * WPAD + (k4 << 2)) = v;
    }
    if (tid < 64) shb[tid] = bias[colbase + tid];
    __syncthreads();

    const int ty = tid >> 3;   // 0..31 -> rows rowbase + ty*8 + i
    const int tx = tid & 7;    // cols 2tx + {0,1,16,17,32,33,48,49}
    const float* wp = shw + (2 * tx) * WPAD;

    // clamped row pointers (loads always in-bounds; stores guarded)
    const long long r0 = rowbase + (long long)ty * 8;
    const float* xp[8];
#pragma unroll
    for (int i = 0; i < 8; ++i) {
        long long r = r0 + i;
        if (r > (long long)n - 1) r = (long long)n - 1;
        xp[i] = xin + (r << 7);
    }

    float acc[8][8];
#pragma unroll
    for (int i = 0; i < 8; ++i)
#pragma unroll
        for (int m = 0; m < 8; ++m) acc[i][m] = 0.0f;

    for (int k4 = 0; k4 < 32; ++k4) {
        const int ko = k4 << 2;
        float4 xr[8];
#pragma unroll
        for (int i = 0; i < 8; ++i) xr[i] = *(const float4*)(xp[i] + ko);
        float4 wc[8];
#pragma unroll
        for (int m = 0; m < 8; ++m) {
            const int joff = ((m & 1) + ((m >> 1) << 4)) * WPAD;
            wc[m] = *(const float4*)(wp + joff + ko);
        }
#pragma unroll
        for (int i = 0; i < 8; ++i)
#pragma unroll
            for (int m = 0; m < 8; ++m)
                acc[i][m] += xr[i].x * wc[m].x + xr[i].y * wc[m].y +
                             xr[i].z * wc[m].z + xr[i].w * wc[m].w;
    }

#pragma unroll
    for (int i = 0; i < 8; ++i) {
        const long long r = r0 + i;
        if (r < n) {
            float* orow = xout + (r << 7) + colbase;
#pragma unroll
            for (int m2 = 0; m2 < 4; ++m2) {
                const int c = 2 * tx + m2 * 16;
                float2 o;
                o.x = acc[i][m2 * 2 + 0] + shb[c + 0];
                o.y = acc[i][m2 * 2 + 1] + shb[c + 1];
                *(float2*)(orow + c) = o;
            }
        }
    }
}

extern "C" void kernel_launch(void* const* d_in, const int* in_sizes, int n_in,
                              void* d_out, int out_size, void* d_ws, size_t ws_size,
                              hipStream_t stream) {
    const float* x = (const float*)d_in[0];
    const int* ei = (const int*)d_in[1];
    const float* Wm = (const float*)d_in[2];
    const float* bias = (const float*)d_in[3];
    float* out = (float*)d_out;

    const int n = in_sizes[0] / D;
    const int E = in_sizes[1] / 2;
    const int NB = (n + SCAN_B - 1) / SCAN_B;

    char* ws = (char*)d_ws;
    size_t off = 0;
    auto alloc = [&](long long bytes) {
        void* p = ws + off;
        off += (size_t)((bytes + 511) & ~511LL);
        return p;
    };
    float* dinv = (float*)alloc((long long)n * 4);
    int* cnt    = (int*)alloc((long long)n * 4);
    int* rp     = (int*)alloc((long long)(n + 1) * 4);
    int* cur    = (int*)alloc((long long)n * 4);
    int* bsum   = (int*)alloc((long long)SCAN_B * 4);
    int2* e8    = (int2*)alloc((long long)E * 8);
    float* x1   = (float*)alloc((long long)n * D * 4);

    const int B = 256;

    k_init<<<ceil_div_ll(n, B), B, 0, stream>>>(dinv, cnt, n);
    k_count<<<ceil_div_ll(E, B), B, 0, stream>>>(ei, dinv, cnt, E);
    k_deg_finalize<<<ceil_div_ll(n, B), B, 0, stream>>>(dinv, n);

    k_scan1<<<NB, SCAN_B, 0, stream>>>(cnt, rp, bsum, n);
    k_scan2<<<1, SCAN_B, 0, stream>>>(bsum, rp, NB, n);
    k_scan3<<<ceil_div_ll(n, B), B, 0, stream>>>(rp, cur, bsum, n);
    k_fill<<<ceil_div_ll(E, B), B, 0, stream>>>(ei, dinv, cur, e8, E);

    // hop 1: out = A_norm @ x
    k_spmm<<<ceil_div_ll(n, 4), B, 0, stream>>>(
        (const float2*)x, rp, e8, dinv, (float2*)out, n);
    // hop 2: x1 = A_norm @ out
    k_spmm<<<ceil_div_ll(n, 4), B, 0, stream>>>(
        (const float2*)out, rp, e8, dinv, (float2*)x1, n);

    // out = x1 @ W^T + b
    dim3 gg(ceil_div_ll(n, 256), 2, 1);
    k_gemm<<<gg, B, 0, stream>>>(x1, Wm, bias, out, n);
}